// Round 11
// baseline (158.438 us; speedup 1.0000x reference)
//
#include <hip/hip_runtime.h>

// dist[pix, o] = ||x[pix]||^2 + ||omega[o]||^2 - 2 * x.omega
// M = 262144 pixels, O = 256 protos, D = 64.
// Round-11: R7 base (nt full-granule loads, plain stores, omega frags in LDS,
// swapped MFMA, 4 blocks/CU). NEW: full-128B-line store coverage WITHOUT LDS.
// For proto-tile pair (2T,2T+1), pixel p's 128B output line [T*128,+128) is
// held by p's 4 lanes (lane = lg*16 + lr, lg=0..3): val0 (words lg*4+0..3)
// and val1 (words 16+lg*4..3). lane^8 pairs pixel p with p+8 at same lg.
// One __shfl_xor(val1, 8) of the FINISHED values lets two store instructions
// each cover 8 pixels x one full 128B line:
//   inst1 (pixels 0..7):  lr<8 store own val0 (words 0..15),
//                         lr>=8 store recv'd val1 of pixel lr-8 (words 16..31)
//   inst2 (pixels 8..15): symmetric.
// If L2 write-allocate issues RFO line-fills for 64B half-line stores
// (603MB real traffic -> 79us bus-limited), this kills the RFO: 335MB.

typedef __attribute__((ext_vector_type(4))) float f32x4;
typedef __attribute__((ext_vector_type(8))) short s16x8;
typedef __attribute__((ext_vector_type(4))) unsigned int u32x4;

constexpr int D_ = 64;
constexpr int O_ = 256;
constexpr int M_ = 16 * 128 * 128;           // 262144
constexpr int ITERS = 4;
constexpr int PIX_PER_BLOCK = 4 * 16 * ITERS; // 256
constexpr int NBLOCKS = M_ / PIX_PER_BLOCK;   // 1024

__device__ __forceinline__ unsigned short f2bf(float f) {
    // round-to-nearest-even fp32 -> bf16
    unsigned u = __builtin_bit_cast(unsigned, f);
    u += 0x7FFFu + ((u >> 16) & 1u);
    return (unsigned short)(u >> 16);
}

__global__ __launch_bounds__(256, 4) void dist_kernel(
    const float* __restrict__ x,
    const float* __restrict__ om,
    float* __restrict__ out)
{
    // [ (t*2+s)*64 + lane ] : per-lane 16B bf16 A-fragment of proto-tile t, k-step s
    __shared__ u32x4 lfrag[32 * 64];          // 32 KiB
    __shared__ __align__(16) float lp2[O_];   // 1 KiB

    const int tid  = threadIdx.x;
    const int wave = tid >> 6;
    const int lane = tid & 63;
    const int lr   = lane & 15;   // A-frag: proto-in-tile ; B-frag/out: pixel-in-tile
    const int lg   = lane >> 4;   // k-group

    // data-k permutation (same for A and B, result-invariant):
    //   frag word j<4  <- data float s*32 + lg*4 + j
    //   frag word j>=4 <- data float s*32 + 16 + lg*4 + (j-4)

    // ---------- once per block: omega -> bf16 fragments + p2, into LDS ------
#pragma unroll
    for (int tt = 0; tt < 4; ++tt) {
        const int t = wave * 4 + tt;
        const float* src = om + (t * 16 + lr) * D_ + lg * 4;
        f32x4 v0 = *(const f32x4*)(src);
        f32x4 v1 = *(const f32x4*)(src + 16);
        f32x4 v2 = *(const f32x4*)(src + 32);
        f32x4 v3 = *(const f32x4*)(src + 48);
        float p2p = 0.f;
        s16x8 f0, f1;
#pragma unroll
        for (int j = 0; j < 4; ++j) {
            f0[j]     = (short)f2bf(v0[j]); p2p += v0[j] * v0[j];
            f0[4 + j] = (short)f2bf(v1[j]); p2p += v1[j] * v1[j];
            f1[j]     = (short)f2bf(v2[j]); p2p += v2[j] * v2[j];
            f1[4 + j] = (short)f2bf(v3[j]); p2p += v3[j] * v3[j];
        }
        lfrag[(t * 2 + 0) * 64 + lane] = __builtin_bit_cast(u32x4, f0);
        lfrag[(t * 2 + 1) * 64 + lane] = __builtin_bit_cast(u32x4, f1);
        p2p += __shfl_xor(p2p, 16);
        p2p += __shfl_xor(p2p, 32);
        if (lg == 0) lp2[t * 16 + lr] = p2p;   // lanes 0..15, conflict-free
    }
    __syncthreads();

    // ---------- steady state: 16 pixels per wave per iteration --------------
    const int pix0 = blockIdx.x * PIX_PER_BLOCK;
    const int p8 = lr & 7;
    const int hi = lr >> 3;   // 0: lanes own pixels 0..7 role; 1: pixels 8..15

    for (int it = 0; it < ITERS; ++it) {
        const int rbase = pix0 + it * 64 + wave * 16;

        // B-frag (x): full-granule nt loads (R7 pattern)
        const float* xs = x + (rbase + lr) * D_ + lg * 4;
        f32x4 a0 = __builtin_nontemporal_load((const f32x4*)(xs));
        f32x4 a1 = __builtin_nontemporal_load((const f32x4*)(xs + 16));
        f32x4 a2 = __builtin_nontemporal_load((const f32x4*)(xs + 32));
        f32x4 a3 = __builtin_nontemporal_load((const f32x4*)(xs + 48));
        s16x8 Bx0, Bx1;
        float x2p = 0.f;
#pragma unroll
        for (int j = 0; j < 4; ++j) {
            Bx0[j]     = (short)f2bf(a0[j]); x2p += a0[j] * a0[j];
            Bx0[4 + j] = (short)f2bf(a1[j]); x2p += a1[j] * a1[j];
            Bx1[j]     = (short)f2bf(a2[j]); x2p += a2[j] * a2[j];
            Bx1[4 + j] = (short)f2bf(a3[j]); x2p += a3[j] * a3[j];
        }
        x2p += __shfl_xor(x2p, 16);
        x2p += __shfl_xor(x2p, 32);

        float* const rowA = out + (size_t)(rbase + p8) * O_;       // pixels 0..7
        float* const rowB = out + (size_t)(rbase + 8 + p8) * O_;   // pixels 8..15

#pragma unroll
        for (int T = 0; T < 8; ++T) {
            const int t0 = 2 * T, t1 = 2 * T + 1;
            s16x8 A00 = __builtin_bit_cast(s16x8, lfrag[(t0 * 2 + 0) * 64 + lane]);
            s16x8 A01 = __builtin_bit_cast(s16x8, lfrag[(t0 * 2 + 1) * 64 + lane]);
            s16x8 A10 = __builtin_bit_cast(s16x8, lfrag[(t1 * 2 + 0) * 64 + lane]);
            s16x8 A11 = __builtin_bit_cast(s16x8, lfrag[(t1 * 2 + 1) * 64 + lane]);
            f32x4 acc0 = {0.f, 0.f, 0.f, 0.f};
            f32x4 acc1 = {0.f, 0.f, 0.f, 0.f};
            acc0 = __builtin_amdgcn_mfma_f32_16x16x32_bf16(A00, Bx0, acc0, 0, 0, 0);
            acc0 = __builtin_amdgcn_mfma_f32_16x16x32_bf16(A01, Bx1, acc0, 0, 0, 0);
            acc1 = __builtin_amdgcn_mfma_f32_16x16x32_bf16(A10, Bx0, acc1, 0, 0, 0);
            acc1 = __builtin_amdgcn_mfma_f32_16x16x32_bf16(A11, Bx1, acc1, 0, 0, 0);

            // epilogue (lane-complete values)
            const f32x4 b40 = *(const f32x4*)&lp2[t0 * 16 + lg * 4];
            const f32x4 b41 = *(const f32x4*)&lp2[t1 * 16 + lg * 4];
            f32x4 val0, val1;
#pragma unroll
            for (int j = 0; j < 4; ++j) {
                val0[j] = (x2p + b40[j]) - 2.f * acc0[j];
                val1[j] = (x2p + b41[j]) - 2.f * acc1[j];
            }

            // exchange val1 across the pixel<->pixel+8 lane pairing
            f32x4 recv;
#pragma unroll
            for (int j = 0; j < 4; ++j)
                recv[j] = __shfl_xor(val1[j], 8);

            f32x4 d1, d2;
#pragma unroll
            for (int j = 0; j < 4; ++j) {
                d1[j] = hi ? recv[j] : val0[j];
                d2[j] = hi ? val0[j] : recv[j];
            }
            // inst1: pixels 0..7, line T fully covered (words 0..31)
            *(f32x4*)(rowA + T * 32 + hi * 16 + lg * 4) = d1;
            // inst2: pixels 8..15, line T fully covered
            *(f32x4*)(rowB + T * 32 + (hi ^ 1) * 16 + lg * 4) = d2;
        }
    }
}

extern "C" void kernel_launch(void* const* d_in, const int* in_sizes, int n_in,
                              void* d_out, int out_size, void* d_ws, size_t ws_size,
                              hipStream_t stream) {
    const float* x  = (const float*)d_in[0];   // [16,128,128,64] fp32
    const float* om = (const float*)d_in[1];   // [256,64] fp32
    float* out = (float*)d_out;                // [16,128,128,256,1] fp32

    dist_kernel<<<dim3(NBLOCKS), dim3(256), 0, stream>>>(x, om, out);
}

// Round 12
// 87.335 us; speedup vs baseline: 1.8141x; 1.8141x over previous
//
#include <hip/hip_runtime.h>

// dist[pix, o] = ||x[pix]||^2 + ||omega[o]||^2 - 2 * x.omega
// M = 262144 pixels, O = 256 protos, D = 64.
// Round-12: R7 instruction shapes exactly (nt full-granule loads, plain
// dwordx4 stores, omega frags in LDS, swapped MFMA). Single change: STREAM
// TOPOLOGY. 1024 blocks -> 256 blocks (ITERS 4 -> 16) and per-wave pixel
// ranges made contiguous: each wave owns a single 256KB contiguous write
// stream (and 64KB read stream) advancing monotonically. ~1024 concurrent
// streams chip-wide (~= the 7 TB/s fill kernel's count) instead of 4096
// interleaved 16KB chunks. Theory: DRAM row-buffer/turnaround thrash scales
// with streams/channel; R11's counters (FETCH 3.7x, write amp 1.35x, all
// pipes idle at 3.9 TB/s) point at memory-system-level waste, not
// instruction-level address geometry.

typedef __attribute__((ext_vector_type(4))) float f32x4;
typedef __attribute__((ext_vector_type(8))) short s16x8;
typedef __attribute__((ext_vector_type(4))) unsigned int u32x4;

constexpr int D_ = 64;
constexpr int O_ = 256;
constexpr int M_ = 16 * 128 * 128;            // 262144
constexpr int ITERS = 16;
constexpr int PIX_PER_WAVE = 16 * ITERS;      // 256 contiguous pixels per wave
constexpr int PIX_PER_BLOCK = 4 * PIX_PER_WAVE; // 1024
constexpr int NBLOCKS = M_ / PIX_PER_BLOCK;   // 256

__device__ __forceinline__ unsigned short f2bf(float f) {
    // round-to-nearest-even fp32 -> bf16
    unsigned u = __builtin_bit_cast(unsigned, f);
    u += 0x7FFFu + ((u >> 16) & 1u);
    return (unsigned short)(u >> 16);
}

__global__ __launch_bounds__(256, 4) void dist_kernel(
    const float* __restrict__ x,
    const float* __restrict__ om,
    float* __restrict__ out)
{
    // [ (t*2+s)*64 + lane ] : per-lane 16B bf16 A-fragment of proto-tile t, k-step s
    __shared__ u32x4 lfrag[32 * 64];          // 32 KiB
    __shared__ __align__(16) float lp2[O_];   // 1 KiB

    const int tid  = threadIdx.x;
    const int wave = tid >> 6;
    const int lane = tid & 63;
    const int lr   = lane & 15;   // A-frag: proto-in-tile ; B-frag/out: pixel-in-tile
    const int lg   = lane >> 4;   // k-group

    // data-k permutation (same for A and B, result-invariant):
    //   frag word j<4  <- data float s*32 + lg*4 + j
    //   frag word j>=4 <- data float s*32 + 16 + lg*4 + (j-4)

    // ---------- once per block: omega -> bf16 fragments + p2, into LDS ------
#pragma unroll
    for (int tt = 0; tt < 4; ++tt) {
        const int t = wave * 4 + tt;
        const float* src = om + (t * 16 + lr) * D_ + lg * 4;
        f32x4 v0 = *(const f32x4*)(src);
        f32x4 v1 = *(const f32x4*)(src + 16);
        f32x4 v2 = *(const f32x4*)(src + 32);
        f32x4 v3 = *(const f32x4*)(src + 48);
        float p2p = 0.f;
        s16x8 f0, f1;
#pragma unroll
        for (int j = 0; j < 4; ++j) {
            f0[j]     = (short)f2bf(v0[j]); p2p += v0[j] * v0[j];
            f0[4 + j] = (short)f2bf(v1[j]); p2p += v1[j] * v1[j];
            f1[j]     = (short)f2bf(v2[j]); p2p += v2[j] * v2[j];
            f1[4 + j] = (short)f2bf(v3[j]); p2p += v3[j] * v3[j];
        }
        lfrag[(t * 2 + 0) * 64 + lane] = __builtin_bit_cast(u32x4, f0);
        lfrag[(t * 2 + 1) * 64 + lane] = __builtin_bit_cast(u32x4, f1);
        p2p += __shfl_xor(p2p, 16);
        p2p += __shfl_xor(p2p, 32);
        if (lg == 0) lp2[t * 16 + lr] = p2p;   // lanes 0..15, conflict-free
    }
    __syncthreads();

    // ---------- steady state: one contiguous 256-pixel range per wave -------
    const int wbase = blockIdx.x * PIX_PER_BLOCK + wave * PIX_PER_WAVE;

    for (int it = 0; it < ITERS; ++it) {
        const int rbase = wbase + it * 16;

        // B-frag (x): lane holds pixel (rbase+lr); full-granule nt loads.
        const float* xs = x + (rbase + lr) * D_ + lg * 4;
        f32x4 a0 = __builtin_nontemporal_load((const f32x4*)(xs));
        f32x4 a1 = __builtin_nontemporal_load((const f32x4*)(xs + 16));
        f32x4 a2 = __builtin_nontemporal_load((const f32x4*)(xs + 32));
        f32x4 a3 = __builtin_nontemporal_load((const f32x4*)(xs + 48));
        s16x8 Bx0, Bx1;
        float x2p = 0.f;
#pragma unroll
        for (int j = 0; j < 4; ++j) {
            Bx0[j]     = (short)f2bf(a0[j]); x2p += a0[j] * a0[j];
            Bx0[4 + j] = (short)f2bf(a1[j]); x2p += a1[j] * a1[j];
            Bx1[j]     = (short)f2bf(a2[j]); x2p += a2[j] * a2[j];
            Bx1[4 + j] = (short)f2bf(a3[j]); x2p += a3[j] * a3[j];
        }
        // full ||x||^2 of pixel (rbase+lr); col of C is lr so no re-shuffle
        x2p += __shfl_xor(x2p, 16);
        x2p += __shfl_xor(x2p, 32);

        float* obase = out + (size_t)(rbase + lr) * O_;

#pragma unroll 4
        for (int t = 0; t < 16; ++t) {
            s16x8 A0 = __builtin_bit_cast(s16x8, lfrag[(t * 2 + 0) * 64 + lane]);
            s16x8 A1 = __builtin_bit_cast(s16x8, lfrag[(t * 2 + 1) * 64 + lane]);
            f32x4 acc = {0.f, 0.f, 0.f, 0.f};
            acc = __builtin_amdgcn_mfma_f32_16x16x32_bf16(A0, Bx0, acc, 0, 0, 0);
            acc = __builtin_amdgcn_mfma_f32_16x16x32_bf16(A1, Bx1, acc, 0, 0, 0);
            // C layout: row(=proto) = lg*4 + j, col(=pixel) = lr
            const f32x4 b4 = *(const f32x4*)&lp2[t * 16 + lg * 4];  // broadcast
            f32x4 val;
#pragma unroll
            for (int j = 0; j < 4; ++j)
                val[j] = (x2p + b4[j]) - 2.f * acc[j];
            *(f32x4*)(obase + t * 16 + lg * 4) = val;   // plain store
        }
    }
}

extern "C" void kernel_launch(void* const* d_in, const int* in_sizes, int n_in,
                              void* d_out, int out_size, void* d_ws, size_t ws_size,
                              hipStream_t stream) {
    const float* x  = (const float*)d_in[0];   // [16,128,128,64] fp32
    const float* om = (const float*)d_in[1];   // [256,64] fp32
    float* out = (float*)d_out;                // [16,128,128,256,1] fp32

    dist_kernel<<<dim3(NBLOCKS), dim3(256), 0, stream>>>(x, om, out);
}

// Round 13
// 71.387 us; speedup vs baseline: 2.2194x; 1.2234x over previous
//
#include <hip/hip_runtime.h>

// dist[pix, o] = ||x[pix]||^2 + ||omega[o]||^2 - 2 * x.omega
// M = 262144 pixels, O = 256 protos, D = 64.
// Round-13: store-REQUEST-width attack based on R11's counter evidence
// (FETCH 249MB >> x's 67MB => write-allocate RFO on the output; R5/R7's
// dwordx4 stores give only 4-lane contiguous runs = 64B requests = partial
// line). Switch MFMA shape to 32x32x16 with A=x (rows=pixels), B=omega
// (cols=protos): C/D layout col=lane&31 => scalar dword stores have 32-lane
// contiguous runs = full 128B line requests (the fill kernel's pattern,
// which shows FETCH~0). No shuffles, no LDS transpose needed.
// k-map: identity k = s*16 + h*8 + j applied to BOTH A and B fragments.

typedef __attribute__((ext_vector_type(4))) float f32x4;
typedef __attribute__((ext_vector_type(16))) float f32x16;
typedef __attribute__((ext_vector_type(8))) short s16x8;
typedef __attribute__((ext_vector_type(4))) unsigned int u32x4;

constexpr int D_ = 64;
constexpr int O_ = 256;
constexpr int M_ = 16 * 128 * 128;              // 262144
constexpr int ITERS = 2;
constexpr int PIX_PER_BLOCK = 4 * 32 * ITERS;   // 256
constexpr int NBLOCKS = M_ / PIX_PER_BLOCK;     // 1024

__device__ __forceinline__ unsigned short f2bf(float f) {
    // round-to-nearest-even fp32 -> bf16
    unsigned u = __builtin_bit_cast(unsigned, f);
    u += 0x7FFFu + ((u >> 16) & 1u);
    return (unsigned short)(u >> 16);
}

__global__ __launch_bounds__(256, 4) void dist_kernel(
    const float* __restrict__ x,
    const float* __restrict__ om,
    float* __restrict__ out)
{
    // [ (T*4+s)*64 + lane ]: 16B bf16 B-fragment of proto-tile T (32 protos),
    // k-step s. Lane (o=lane&31, h=lane>>5) holds omega[T*32+o][s*16+h*8 ..+8).
    __shared__ u32x4 lfrag[32 * 64];          // 32 KiB
    __shared__ __align__(16) float lp2[O_];   // 1 KiB

    const int tid  = threadIdx.x;
    const int wave = tid >> 6;
    const int lane = tid & 63;
    const int p    = lane & 31;   // A: pixel row ; B: proto col ; store col
    const int h    = lane >> 5;   // k-half

    // ---------- once per block: omega -> bf16 fragments + p2 ---------------
#pragma unroll
    for (int tt = 0; tt < 2; ++tt) {
        const int T = wave * 2 + tt;
        float p2p = 0.f;
#pragma unroll
        for (int s = 0; s < 4; ++s) {
            const float* src = om + (T * 32 + p) * D_ + s * 16 + h * 8;
            f32x4 v0 = *(const f32x4*)(src);
            f32x4 v1 = *(const f32x4*)(src + 4);
            s16x8 f;
#pragma unroll
            for (int j = 0; j < 4; ++j) {
                f[j]     = (short)f2bf(v0[j]); p2p += v0[j] * v0[j];
                f[4 + j] = (short)f2bf(v1[j]); p2p += v1[j] * v1[j];
            }
            lfrag[(T * 4 + s) * 64 + lane] = __builtin_bit_cast(u32x4, f);
        }
        p2p += __shfl_xor(p2p, 32);           // join the two k-halves
        if (lane < 32) lp2[T * 32 + p] = p2p;
    }
    __syncthreads();

    float p2r[8];
#pragma unroll
    for (int T = 0; T < 8; ++T) p2r[T] = lp2[T * 32 + p];  // 2-way bcast, free

    // ---------- steady state: 32 pixels per wave per iteration --------------
    const int pix0 = blockIdx.x * PIX_PER_BLOCK;

    for (int it = 0; it < ITERS; ++it) {
        const int rbase = pix0 + it * 128 + wave * 32;

        // A-frag: lane (p,h) holds x[rbase+p][s*16 + h*8 ..+8) for s=0..3
        const float* xs = x + (size_t)(rbase + p) * D_ + h * 8;
        s16x8 Af[4];
        float x2p = 0.f;
#pragma unroll
        for (int s = 0; s < 4; ++s) {
            f32x4 a0 = __builtin_nontemporal_load((const f32x4*)(xs + s * 16));
            f32x4 a1 = __builtin_nontemporal_load((const f32x4*)(xs + s * 16 + 4));
#pragma unroll
            for (int j = 0; j < 4; ++j) {
                Af[s][j]     = (short)f2bf(a0[j]); x2p += a0[j] * a0[j];
                Af[s][4 + j] = (short)f2bf(a1[j]); x2p += a1[j] * a1[j];
            }
        }
        x2p += __shfl_xor(x2p, 32);           // full ||x||^2 of pixel p

        // x2 for the 16 C-rows this lane will store: row = (reg&3)+8*(reg>>2)+4h
        float x2r[16];
#pragma unroll
        for (int reg = 0; reg < 16; ++reg)
            x2r[reg] = __shfl(x2p, (reg & 3) + 8 * (reg >> 2) + 4 * h);

        // base: row offset 4h baked in; col = p
        float* const obase = out + (size_t)(rbase + 4 * h) * O_ + p;

#pragma unroll
        for (int T = 0; T < 8; ++T) {
            f32x16 acc = {0.f, 0.f, 0.f, 0.f, 0.f, 0.f, 0.f, 0.f,
                          0.f, 0.f, 0.f, 0.f, 0.f, 0.f, 0.f, 0.f};
#pragma unroll
            for (int s = 0; s < 4; ++s) {
                s16x8 Bf = __builtin_bit_cast(s16x8, lfrag[(T * 4 + s) * 64 + lane]);
                acc = __builtin_amdgcn_mfma_f32_32x32x16_bf16(Af[s], Bf, acc, 0, 0, 0);
            }
            // epilogue + store: scalar dword, lanes 0..31 = protos T*32..+31
            // contiguous -> two full 128B line requests per instruction
#pragma unroll
            for (int reg = 0; reg < 16; ++reg) {
                const float val = (x2r[reg] + p2r[T]) - 2.f * acc[reg];
                obase[((reg & 3) + 8 * (reg >> 2)) * O_ + T * 32] = val;
            }
        }
    }
}

extern "C" void kernel_launch(void* const* d_in, const int* in_sizes, int n_in,
                              void* d_out, int out_size, void* d_ws, size_t ws_size,
                              hipStream_t stream) {
    const float* x  = (const float*)d_in[0];   // [16,128,128,64] fp32
    const float* om = (const float*)d_in[1];   // [256,64] fp32
    float* out = (float*)d_out;                // [16,128,128,256,1] fp32

    dist_kernel<<<dim3(NBLOCKS), dim3(256), 0, stream>>>(x, om, out);
}